// Round 6
// baseline (473.459 us; speedup 1.0000x reference)
//
#include <hip/hip_runtime.h>
#include <cstdint>

typedef unsigned short u16;
typedef __attribute__((ext_vector_type(8))) short s16x8;
typedef __attribute__((ext_vector_type(4))) float f32x4;
typedef __attribute__((ext_vector_type(8))) unsigned short u16x8;
typedef __attribute__((ext_vector_type(4))) unsigned short u16x4;

#define B_ 128
#define T_ 512
#define C_ 512
#define TC 262144

static __device__ __forceinline__ float bf2f(u16 u) {
  union { unsigned int i; float f; } v; v.i = ((unsigned int)u) << 16; return v.f;
}
static __device__ __forceinline__ u16 f2bf(float f) {
  union { float fv; unsigned int i; } v; v.fv = f;
  unsigned int r = (v.i + 0x7FFFu + ((v.i >> 16) & 1u)) >> 16;
  return (u16)r;
}

// x*sigmoid(2z) form of tanh-GELU (algebraically identical to the version
// that passed with absmax 0.031).
static __device__ __forceinline__ float gelu_fast(float x) {
  float x2 = x * x;
  float arg = 1.5957691216057308f * x * fmaf(0.044715f, x2, 1.0f);
  return x / (1.0f + __expf(-arg));
}

#define GLD16(gp, lp) __builtin_amdgcn_global_load_lds( \
    (const __attribute__((address_space(1))) void*)(gp), \
    (__attribute__((address_space(3))) void*)(lp), 16, 0, 0)

// ---------------- LN1 stats: two-stage deterministic reduction ----------------

__global__ __launch_bounds__(256)
void reduce_stats_kernel(const float* __restrict__ X, float2* __restrict__ partials) {
  const int b = blockIdx.y, blk = blockIdx.x, tid = threadIdx.x;
  const float* p = X + (size_t)b * TC + (size_t)blk * 2048 + (size_t)tid * 8;
  f32x4 v0 = *(const f32x4*)p;
  f32x4 v1 = *(const f32x4*)(p + 4);
  float s = 0.f, q = 0.f;
#pragma unroll
  for (int i = 0; i < 4; ++i) { s += v0[i] + v1[i]; q += v0[i] * v0[i] + v1[i] * v1[i]; }
  for (int o = 32; o; o >>= 1) { s += __shfl_down(s, o); q += __shfl_down(q, o); }
  __shared__ float ss[4], qq[4];
  if ((tid & 63) == 0) { ss[tid >> 6] = s; qq[tid >> 6] = q; }
  __syncthreads();
  if (tid == 0)
    partials[(size_t)b * 128 + blk] =
        make_float2(ss[0] + ss[1] + ss[2] + ss[3], qq[0] + qq[1] + qq[2] + qq[3]);
}

__global__ __launch_bounds__(128)
void finalize_stats_kernel(const float2* __restrict__ partials, float2* __restrict__ stats) {
  const int b = blockIdx.x, tid = threadIdx.x;
  float2 v = partials[(size_t)b * 128 + tid];
  float s = v.x, q = v.y;
  for (int o = 32; o; o >>= 1) { s += __shfl_down(s, o); q += __shfl_down(q, o); }
  __shared__ float ss[2], qq[2];
  if ((tid & 63) == 0) { ss[tid >> 6] = s; qq[tid >> 6] = q; }
  __syncthreads();
  if (tid == 0) {
    float sm = ss[0] + ss[1], sq = qq[0] + qq[1];
    float mean = sm * (1.f / (float)TC);
    float var = sq * (1.f / (float)TC) - mean * mean;
    stats[b] = make_float2(mean, rsqrtf(var + 1e-5f));
  }
}

// finalize for 4 partials per batch (TriU-epilogue fused LN2 stats)
__global__ __launch_bounds__(64)
void finalize_stats4_kernel(const float2* __restrict__ partials, float2* __restrict__ stats) {
  const int b = blockIdx.x, tid = threadIdx.x;
  float s = 0.f, q = 0.f;
  if (tid < 4) { float2 v = partials[(size_t)b * 4 + tid]; s = v.x; q = v.y; }
  for (int o = 2; o; o >>= 1) { s += __shfl_down(s, o); q += __shfl_down(q, o); }
  if (tid == 0) {
    float mean = s * (1.f / (float)TC);
    float var = q * (1.f / (float)TC) - mean * mean;
    stats[b] = make_float2(mean, rsqrtf(var + 1e-5f));
  }
}

// --------- LN1 apply + transpose: x^T[b][c][t] = bf16(LN(inputs)) ----------

__global__ __launch_bounds__(256)
void ln1_transpose_kernel(const float* __restrict__ X, const float* __restrict__ W,
                          const float* __restrict__ Bv, const float2* __restrict__ stats,
                          u16* __restrict__ xT) {
  const int b = blockIdx.z;
  const int t0 = blockIdx.y * 64, c0 = blockIdx.x * 64;
  const float2 st = stats[b];
  const float mu = st.x, rs = st.y;
  __shared__ u16 tile[64][72];
  const int tid = threadIdx.x;
  const int rr = tid >> 4;
  const int cc = (tid & 15) * 4;
#pragma unroll
  for (int i = 0; i < 4; ++i) {
    const int lt = i * 16 + rr;
    const size_t wi = (size_t)(t0 + lt) * C_ + c0 + cc;
    f32x4 x = *(const f32x4*)(X + (size_t)b * TC + wi);
    f32x4 w = *(const f32x4*)(W + wi);
    f32x4 bb = *(const f32x4*)(Bv + wi);
#pragma unroll
    for (int j = 0; j < 4; ++j)
      tile[lt][cc + j] = f2bf((x[j] - mu) * rs * w[j] + bb[j]);
  }
  __syncthreads();
  const int c = tid >> 2;
  const int tg = (tid & 3) * 16;
  u16 buf[16];
#pragma unroll
  for (int i = 0; i < 16; ++i) buf[i] = tile[tg + i][c];
  const size_t o = (size_t)b * TC + (size_t)(c0 + c) * T_ + t0 + tg;
  u16x8 o0, o1;
#pragma unroll
  for (int i = 0; i < 8; ++i) { o0[i] = buf[i]; o1[i] = buf[8 + i]; }
  *(u16x8*)(xT + o) = o0;
  *(u16x8*)(xT + o + 8) = o1;
}

// ------------------- LN2 apply (elementwise, bf16 input) -------------------

__global__ __launch_bounds__(256)
void ln2_apply_kernel(const u16* __restrict__ S, const float* __restrict__ W,
                      const float* __restrict__ Bv, const float2* __restrict__ stats,
                      u16* __restrict__ x2) {
  const size_t i = ((size_t)blockIdx.x * 256 + threadIdx.x) * 8;
  const int b = (int)(i >> 18);
  const size_t r = i & (size_t)(TC - 1);
  const float2 st = stats[b];
  const float mu = st.x, rs = st.y;
  u16x8 sv = *(const u16x8*)(S + i);
  f32x4 w0 = *(const f32x4*)(W + r);
  f32x4 w1 = *(const f32x4*)(W + r + 4);
  f32x4 b0 = *(const f32x4*)(Bv + r);
  f32x4 b1 = *(const f32x4*)(Bv + r + 4);
  u16x8 o;
#pragma unroll
  for (int j = 0; j < 4; ++j) {
    o[j]     = f2bf((bf2f(sv[j])     - mu) * rs * w0[j] + b0[j]);
    o[4 + j] = f2bf((bf2f(sv[4 + j]) - mu) * rs * w1[j] + b1[j]);
  }
  *(u16x8*)(x2 + i) = o;
}

// --------------------------- weight conversions ----------------------------

__global__ __launch_bounds__(256)
void cvt_bf16_kernel(const float* __restrict__ X, u16* __restrict__ Y) {
  const size_t i = ((size_t)blockIdx.x * 256 + threadIdx.x) * 4;
  f32x4 v = *(const f32x4*)(X + i);
  u16x4 o;
#pragma unroll
  for (int j = 0; j < 4; ++j) o[j] = f2bf(v[j]);
  *(u16x4*)(Y + i) = o;
}

__global__ __launch_bounds__(256)
void tril_bf16_kernel(const float* __restrict__ Wt, u16* __restrict__ Y) {
  const int i = blockIdx.x * 256 + threadIdx.x;
  const int s = i >> 9, t = i & 511;
  Y[i] = f2bf(t <= s ? Wt[i] : 0.f);
}

// -------------- BT-layout MFMA GEMM, 256x256 tile, 8 waves -----------------
// K-loop identical to round 5 (proven: bank-conflict 0). NEW: LDS-staged
// epilogue — acc fragments scattered into a swizzled 128KB LDS C-tile
// (reusing the As/Bs union), then flushed with coalesced 16B global ops;
// residual reads and bias adds ride the coalesced flush. MODE 2 (fp32 C,
// 256KB) flushes in two 128-row phases keyed off the wave's row-half.
// MODE 0: TriU  (z-batched; C=bf16 s = acc + inputs + triu_b[row]; tri K-skip;
//               fused per-block LN2 partial stats)
// MODE 1: fc1   (C=bf16 h = gelu(acc + fc1_b[col]))
// MODE 2: fc2   (C=fp32 out = acc + fc2_b[col] + x2[idx])

template <int MODE>
__global__ __launch_bounds__(512, 2)
void gemm_bt_kernel(const u16* __restrict__ A, const u16* __restrict__ Bm,
                    int K, int lda, int ldb,
                    void* __restrict__ Cp, int ldc,
                    const float* __restrict__ bias,
                    const void* __restrict__ res,
                    long long strideB, long long strideC,
                    float2* __restrict__ stat_part) {
  __shared__ u16 smem[65536];          // 128KB union: As|Bs during K-loop, C-tile in epilogue
  __shared__ float rs_[8], rq_[8];
  u16* Asb = smem;                     // [2][256*64]
  u16* Bsb = smem + 32768;             // [2][256*64]
  const int tid = threadIdx.x;

  // --- XCD-aware bijective remap (nwg % 8 == 0 for all launches) ---
  const int nwg = gridDim.x;
  const int orig = blockIdx.x;
  const int swz = (orig & 7) * (nwg >> 3) + (orig >> 3);
  int bx, by, bz;
  if (MODE == 0) { bz = swz >> 2; by = (swz >> 1) & 1; bx = swz & 1; }
  else if (MODE == 1) { bz = 0; by = swz >> 2; bx = swz & 3; }
  else { bz = 0; by = swz >> 1; bx = swz & 1; }

  const u16* Bp = Bm + (size_t)bz * (size_t)strideB;
  const int m0 = by * 256, n0 = bx * 256;
  int kTiles = K >> 6;
  if (MODE == 0) { const int need = (by + 1) * 4; if (need < kTiles) kTiles = need; }

  const int lane = tid & 63;
  const int wave = tid >> 6;
  const int wm = (wave >> 2) * 128;   // 2 wave-rows of 128
  const int wn = (wave & 3) * 64;     // 4 wave-cols of 64
  const int lr = lane & 15;
  const int kg = lane >> 4;

  f32x4 acc[8][4];
  const f32x4 zero = {0.f, 0.f, 0.f, 0.f};
#pragma unroll
  for (int m = 0; m < 8; ++m)
#pragma unroll
    for (int n = 0; n < 4; ++n) acc[m][n] = zero;

  // Staging: A = 256 rows x 128B = 2048 16B-chunks; source col-chunk XOR
  // (r&7) so swizzled ds_reads see linear data (LDS dest stays linear).
  auto STAGE = [&](int buf, int kt) {
    const int k0 = kt << 6;
#pragma unroll
    for (int p = 0; p < 4; ++p) {
      const int q = p * 512 + tid;
      const int r = q >> 3;
      const int kcs = (q & 7) ^ (r & 7);
      GLD16(A + (size_t)(m0 + r) * lda + k0 + (kcs << 3), &Asb[buf * 16384 + q * 8]);
    }
#pragma unroll
    for (int p = 0; p < 4; ++p) {
      const int q = p * 512 + tid;
      const int r = q >> 3;
      const int kcs = (q & 7) ^ (r & 7);
      GLD16(Bp + (size_t)(n0 + r) * ldb + k0 + (kcs << 3), &Bsb[buf * 16384 + q * 8]);
    }
  };

  STAGE(0, 0);
  int cur = 0;
  for (int kt = 0; kt < kTiles; ++kt) {
    __syncthreads();                      // buf[cur] landed; prior reads done
    if (kt + 1 < kTiles) STAGE(cur ^ 1, kt + 1);   // overlaps MFMA below
#pragma unroll
    for (int kk = 0; kk < 2; ++kk) {
      s16x8 af[8], bf4[4];
#pragma unroll
      for (int m = 0; m < 8; ++m) {
        const int row = wm + m * 16 + lr;
        const int ch = (kk * 4 + kg) ^ (row & 7);
        af[m] = *(const s16x8*)&Asb[cur * 16384 + row * 64 + ch * 8];
      }
#pragma unroll
      for (int n = 0; n < 4; ++n) {
        const int row = wn + n * 16 + lr;
        const int ch = (kk * 4 + kg) ^ (row & 7);
        bf4[n] = *(const s16x8*)&Bsb[cur * 16384 + row * 64 + ch * 8];
      }
#pragma unroll
      for (int m = 0; m < 8; ++m)
#pragma unroll
        for (int n = 0; n < 4; ++n)
          acc[m][n] = __builtin_amdgcn_mfma_f32_16x16x32_bf16(af[m], bf4[n], acc[m][n], 0, 0, 0);
    }
    cur ^= 1;
  }

  __syncthreads();   // all waves done with As/Bs; smem becomes the C-tile
  char* ep = (char*)smem;

  if (MODE == 0) {
    u16* Cptr = (u16*)Cp + (size_t)bz * (size_t)strideC;
    const float* inp = (const float*)res + (size_t)bz * (size_t)strideC;
    // scatter bf16(acc) into swizzled ep[256 rows][512B]
#pragma unroll
    for (int m = 0; m < 8; ++m)
#pragma unroll
      for (int n = 0; n < 4; ++n) {
        const int col = wn + n * 16 + lr;
#pragma unroll
        for (int j = 0; j < 4; ++j) {
          const int row = wm + m * 16 + kg * 4 + j;
          const int byt = row * 512 + ((((col >> 3) ^ (row & 31)) << 4)) + (col & 7) * 2;
          *(u16*)(ep + byt) = f2bf(acc[m][n][j]);
        }
      }
    __syncthreads();
    // coalesced flush: + inputs + triu_b[row], fused LN2 partial stats
    const int frow = tid >> 1;
    const int fhalf = tid & 1;
    const int grow = m0 + frow;
    const float bs = bias[grow];
    u16* Crow = Cptr + (size_t)grow * ldc + n0 + fhalf * 128;
    const float* irow = inp + (size_t)grow * ldc + n0 + fhalf * 128;
    float psum = 0.f, psq = 0.f;
#pragma unroll
    for (int c16 = 0; c16 < 16; ++c16) {
      const int c = fhalf * 16 + c16;
      u16x8 e = *(const u16x8*)(ep + frow * 512 + ((c ^ (frow & 31)) << 4));
      f32x4 i0 = *(const f32x4*)(irow + c16 * 8);
      f32x4 i1 = *(const f32x4*)(irow + c16 * 8 + 4);
      u16x8 o;
#pragma unroll
      for (int k = 0; k < 4; ++k) {
        float v0 = bf2f(e[k]) + i0[k] + bs;
        float v1 = bf2f(e[4 + k]) + i1[k] + bs;
        psum += v0 + v1; psq += v0 * v0 + v1 * v1;
        o[k] = f2bf(v0); o[4 + k] = f2bf(v1);
      }
      *(u16x8*)(Crow + c16 * 8) = o;
    }
    for (int sh = 32; sh; sh >>= 1) { psum += __shfl_down(psum, sh); psq += __shfl_down(psq, sh); }
    if (lane == 0) { rs_[wave] = psum; rq_[wave] = psq; }
    __syncthreads();
    if (tid == 0) {
      float s = 0.f, q = 0.f;
#pragma unroll
      for (int w = 0; w < 8; ++w) { s += rs_[w]; q += rq_[w]; }
      stat_part[(size_t)bz * 4 + by * 2 + bx] = make_float2(s, q);
    }
  } else if (MODE == 1) {
    u16* Cptr = (u16*)Cp;
    // scatter bf16(gelu(acc + fc1_b[col])) into swizzled ep
#pragma unroll
    for (int m = 0; m < 8; ++m)
#pragma unroll
      for (int n = 0; n < 4; ++n) {
        const int coll = wn + n * 16 + lr;
        const float bsn = bias[n0 + coll];
#pragma unroll
        for (int j = 0; j < 4; ++j) {
          const int row = wm + m * 16 + kg * 4 + j;
          const int byt = row * 512 + ((((coll >> 3) ^ (row & 31)) << 4)) + (coll & 7) * 2;
          *(u16*)(ep + byt) = f2bf(gelu_fast(acc[m][n][j] + bsn));
        }
      }
    __syncthreads();
    const int frow = tid >> 1;
    const int fhalf = tid & 1;
    const int grow = m0 + frow;
    u16* Crow = Cptr + (size_t)grow * ldc + n0 + fhalf * 128;
#pragma unroll
    for (int c16 = 0; c16 < 16; ++c16) {
      const int c = fhalf * 16 + c16;
      u16x8 e = *(const u16x8*)(ep + frow * 512 + ((c ^ (frow & 31)) << 4));
      *(u16x8*)(Crow + c16 * 8) = e;
    }
  } else {
    float* Cptr = (float*)Cp;
    const u16* x2p = (const u16*)res;
    // two 128-row phases: fp32 half-tile = 128KB
#pragma unroll
    for (int half = 0; half < 2; ++half) {
      if ((wave >> 2) == half) {
#pragma unroll
        for (int m = 0; m < 8; ++m)
#pragma unroll
          for (int n = 0; n < 4; ++n) {
            const int coll = wn + n * 16 + lr;
#pragma unroll
            for (int j = 0; j < 4; ++j) {
              const int lrow = m * 16 + kg * 4 + j;   // 0..127 (wm-relative)
              const int byt = lrow * 1024 + ((((coll >> 2) ^ (lrow & 63)) << 4)) + (coll & 3) * 4;
              *(float*)(ep + byt) = acc[m][n][j];
            }
          }
      }
      __syncthreads();
      const int frow = tid >> 2;       // 0..127
      const int seg = tid & 3;
      const int grow = m0 + half * 128 + frow;
      float* Crow = Cptr + (size_t)grow * ldc + n0;
      const u16* xrow = x2p + (size_t)grow * ldc + n0;
#pragma unroll
      for (int c4 = 0; c4 < 16; ++c4) {
        const int c = seg * 16 + c4;                 // chunk 0..63
        f32x4 a = *(const f32x4*)(ep + frow * 1024 + ((c ^ (frow & 63)) << 4));
        const int col0 = c * 4;
        f32x4 bv = *(const f32x4*)(bias + n0 + col0);
        u16x4 xv = *(const u16x4*)(xrow + col0);
        f32x4 o;
#pragma unroll
        for (int k = 0; k < 4; ++k) o[k] = a[k] + bv[k] + bf2f(xv[k]);
        *(f32x4*)(Crow + col0) = o;
      }
      __syncthreads();
    }
  }
}

// -------------------------------- launcher ---------------------------------

extern "C" void kernel_launch(void* const* d_in, const int* in_sizes, int n_in,
                              void* d_out, int out_size, void* d_ws, size_t ws_size,
                              hipStream_t stream) {
  const float* inputs = (const float*)d_in[0];
  const float* ln1_w  = (const float*)d_in[1];
  const float* ln1_b  = (const float*)d_in[2];
  const float* ln2_w  = (const float*)d_in[3];
  const float* ln2_b  = (const float*)d_in[4];
  const float* triu_W = (const float*)d_in[5];
  const float* triu_b = (const float*)d_in[6];
  const float* fc1_W  = (const float*)d_in[7];
  const float* fc1_b  = (const float*)d_in[8];
  const float* fc2_W  = (const float*)d_in[9];
  const float* fc2_b  = (const float*)d_in[10];
  float* out = (float*)d_out;
  (void)in_sizes; (void)n_in; (void)out_size; (void)ws_size;

  char* ws = (char*)d_ws;
  size_t off = 0;
  auto carve = [&](size_t bytes) {
    char* p = ws + off;
    off += (bytes + 255) & ~(size_t)255;
    return p;
  };
  u16* s_bf = (u16*)carve((size_t)B_ * T_ * C_ * 2);   // 67MB bf16 s = mix+inputs+bias
  u16* xT   = (u16*)carve((size_t)B_ * T_ * C_ * 2);   // 67MB; reused as x2
  u16* x2   = xT;
  u16* h    = (u16*)carve((size_t)B_ * T_ * 2 * C_ * 2); // 134MB bf16
  u16* wmb  = (u16*)carve((size_t)T_ * T_ * 2);
  u16* w1b  = (u16*)carve((size_t)2 * C_ * C_ * 2);
  u16* w2b  = (u16*)carve((size_t)C_ * 2 * C_ * 2);
  float2* partials  = (float2*)carve(128 * 128 * sizeof(float2));
  float2* partials2 = (float2*)carve(128 * 4 * sizeof(float2));
  float2* stats1 = (float2*)carve(128 * sizeof(float2));
  float2* stats2 = (float2*)carve(128 * sizeof(float2));

  // LN1 stats
  reduce_stats_kernel<<<dim3(128, 128), 256, 0, stream>>>(inputs, partials);
  finalize_stats_kernel<<<128, 128, 0, stream>>>(partials, stats1);
  // LN1 apply + transpose -> xT (bf16)
  ln1_transpose_kernel<<<dim3(8, 8, 128), 256, 0, stream>>>(inputs, ln1_w, ln1_b, stats1, xT);
  // weight prep
  tril_bf16_kernel<<<1024, 256, 0, stream>>>(triu_W, wmb);
  cvt_bf16_kernel<<<512, 256, 0, stream>>>(fc1_W, w1b);
  cvt_bf16_kernel<<<512, 256, 0, stream>>>(fc2_W, w2b);
  // TriU mix: s = tril(W) @ x + triu_b + inputs (bf16 out) + fused LN2 partial stats
  gemm_bt_kernel<0><<<512, 512, 0, stream>>>(
      wmb, xT, 512, 512, 512, s_bf, 512, triu_b, inputs, (long long)TC, (long long)TC, partials2);
  finalize_stats4_kernel<<<128, 64, 0, stream>>>(partials2, stats2);
  // LN2 apply -> x2 (bf16)
  ln2_apply_kernel<<<16384, 256, 0, stream>>>(s_bf, ln2_w, ln2_b, stats2, x2);
  // fc1 + GELU -> h (bf16)
  gemm_bt_kernel<1><<<1024, 512, 0, stream>>>(
      x2, w1b, 512, 512, 512, h, 1024, fc1_b, nullptr, 0, 0, nullptr);
  // fc2 + bias + residual -> out (fp32)
  gemm_bt_kernel<2><<<512, 512, 0, stream>>>(
      h, w2b, 1024, 1024, 1024, out, 512, fc2_b, x2, 0, 0, nullptr);
}

// Round 7
// 382.467 us; speedup vs baseline: 1.2379x; 1.2379x over previous
//
#include <hip/hip_runtime.h>
#include <cstdint>

typedef unsigned short u16;
typedef __attribute__((ext_vector_type(8))) short s16x8;
typedef __attribute__((ext_vector_type(4))) float f32x4;
typedef __attribute__((ext_vector_type(8))) unsigned short u16x8;
typedef __attribute__((ext_vector_type(4))) unsigned short u16x4;

#define B_ 128
#define T_ 512
#define C_ 512
#define TC 262144

static __device__ __forceinline__ float bf2f(u16 u) {
  union { unsigned int i; float f; } v; v.i = ((unsigned int)u) << 16; return v.f;
}
static __device__ __forceinline__ u16 f2bf(float f) {
  union { float fv; unsigned int i; } v; v.fv = f;
  unsigned int r = (v.i + 0x7FFFu + ((v.i >> 16) & 1u)) >> 16;
  return (u16)r;
}

// x*sigmoid(2z) form of tanh-GELU (algebraically identical to the version
// that passed with absmax 0.031).
static __device__ __forceinline__ float gelu_fast(float x) {
  float x2 = x * x;
  float arg = 1.5957691216057308f * x * fmaf(0.044715f, x2, 1.0f);
  return x / (1.0f + __expf(-arg));
}

#define GLD16(gp, lp) __builtin_amdgcn_global_load_lds( \
    (const __attribute__((address_space(1))) void*)(gp), \
    (__attribute__((address_space(3))) void*)(lp), 16, 0, 0)

// ---------------- LN1 stats: two-stage deterministic reduction ----------------

__global__ __launch_bounds__(256)
void reduce_stats_kernel(const float* __restrict__ X, float2* __restrict__ partials) {
  const int b = blockIdx.y, blk = blockIdx.x, tid = threadIdx.x;
  const float* p = X + (size_t)b * TC + (size_t)blk * 2048 + (size_t)tid * 8;
  f32x4 v0 = *(const f32x4*)p;
  f32x4 v1 = *(const f32x4*)(p + 4);
  float s = 0.f, q = 0.f;
#pragma unroll
  for (int i = 0; i < 4; ++i) { s += v0[i] + v1[i]; q += v0[i] * v0[i] + v1[i] * v1[i]; }
  for (int o = 32; o; o >>= 1) { s += __shfl_down(s, o); q += __shfl_down(q, o); }
  __shared__ float ss[4], qq[4];
  if ((tid & 63) == 0) { ss[tid >> 6] = s; qq[tid >> 6] = q; }
  __syncthreads();
  if (tid == 0)
    partials[(size_t)b * 128 + blk] =
        make_float2(ss[0] + ss[1] + ss[2] + ss[3], qq[0] + qq[1] + qq[2] + qq[3]);
}

__global__ __launch_bounds__(128)
void finalize_stats_kernel(const float2* __restrict__ partials, float2* __restrict__ stats) {
  const int b = blockIdx.x, tid = threadIdx.x;
  float2 v = partials[(size_t)b * 128 + tid];
  float s = v.x, q = v.y;
  for (int o = 32; o; o >>= 1) { s += __shfl_down(s, o); q += __shfl_down(q, o); }
  __shared__ float ss[2], qq[2];
  if ((tid & 63) == 0) { ss[tid >> 6] = s; qq[tid >> 6] = q; }
  __syncthreads();
  if (tid == 0) {
    float sm = ss[0] + ss[1], sq = qq[0] + qq[1];
    float mean = sm * (1.f / (float)TC);
    float var = sq * (1.f / (float)TC) - mean * mean;
    stats[b] = make_float2(mean, rsqrtf(var + 1e-5f));
  }
}

// finalize for 4 partials per batch (TriU-epilogue fused LN2 stats)
__global__ __launch_bounds__(64)
void finalize_stats4_kernel(const float2* __restrict__ partials, float2* __restrict__ stats) {
  const int b = blockIdx.x, tid = threadIdx.x;
  float s = 0.f, q = 0.f;
  if (tid < 4) { float2 v = partials[(size_t)b * 4 + tid]; s = v.x; q = v.y; }
  for (int o = 2; o; o >>= 1) { s += __shfl_down(s, o); q += __shfl_down(q, o); }
  if (tid == 0) {
    float mean = s * (1.f / (float)TC);
    float var = q * (1.f / (float)TC) - mean * mean;
    stats[b] = make_float2(mean, rsqrtf(var + 1e-5f));
  }
}

// --------- LN1 apply + transpose: x^T[b][c][t] = bf16(LN(inputs)) ----------

__global__ __launch_bounds__(256)
void ln1_transpose_kernel(const float* __restrict__ X, const float* __restrict__ W,
                          const float* __restrict__ Bv, const float2* __restrict__ stats,
                          u16* __restrict__ xT) {
  const int b = blockIdx.z;
  const int t0 = blockIdx.y * 64, c0 = blockIdx.x * 64;
  const float2 st = stats[b];
  const float mu = st.x, rs = st.y;
  __shared__ u16 tile[64][72];
  const int tid = threadIdx.x;
  const int rr = tid >> 4;
  const int cc = (tid & 15) * 4;
#pragma unroll
  for (int i = 0; i < 4; ++i) {
    const int lt = i * 16 + rr;
    const size_t wi = (size_t)(t0 + lt) * C_ + c0 + cc;
    f32x4 x = *(const f32x4*)(X + (size_t)b * TC + wi);
    f32x4 w = *(const f32x4*)(W + wi);
    f32x4 bb = *(const f32x4*)(Bv + wi);
#pragma unroll
    for (int j = 0; j < 4; ++j)
      tile[lt][cc + j] = f2bf((x[j] - mu) * rs * w[j] + bb[j]);
  }
  __syncthreads();
  const int c = tid >> 2;
  const int tg = (tid & 3) * 16;
  u16 buf[16];
#pragma unroll
  for (int i = 0; i < 16; ++i) buf[i] = tile[tg + i][c];
  const size_t o = (size_t)b * TC + (size_t)(c0 + c) * T_ + t0 + tg;
  u16x8 o0, o1;
#pragma unroll
  for (int i = 0; i < 8; ++i) { o0[i] = buf[i]; o1[i] = buf[8 + i]; }
  *(u16x8*)(xT + o) = o0;
  *(u16x8*)(xT + o + 8) = o1;
}

// ------------------- LN2 apply (elementwise, bf16 input) -------------------

__global__ __launch_bounds__(256)
void ln2_apply_kernel(const u16* __restrict__ S, const float* __restrict__ W,
                      const float* __restrict__ Bv, const float2* __restrict__ stats,
                      u16* __restrict__ x2) {
  const size_t i = ((size_t)blockIdx.x * 256 + threadIdx.x) * 8;
  const int b = (int)(i >> 18);
  const size_t r = i & (size_t)(TC - 1);
  const float2 st = stats[b];
  const float mu = st.x, rs = st.y;
  u16x8 sv = *(const u16x8*)(S + i);
  f32x4 w0 = *(const f32x4*)(W + r);
  f32x4 w1 = *(const f32x4*)(W + r + 4);
  f32x4 b0 = *(const f32x4*)(Bv + r);
  f32x4 b1 = *(const f32x4*)(Bv + r + 4);
  u16x8 o;
#pragma unroll
  for (int j = 0; j < 4; ++j) {
    o[j]     = f2bf((bf2f(sv[j])     - mu) * rs * w0[j] + b0[j]);
    o[4 + j] = f2bf((bf2f(sv[4 + j]) - mu) * rs * w1[j] + b1[j]);
  }
  *(u16x8*)(x2 + i) = o;
}

// --------------------------- weight conversions ----------------------------

__global__ __launch_bounds__(256)
void cvt_bf16_kernel(const float* __restrict__ X, u16* __restrict__ Y) {
  const size_t i = ((size_t)blockIdx.x * 256 + threadIdx.x) * 4;
  f32x4 v = *(const f32x4*)(X + i);
  u16x4 o;
#pragma unroll
  for (int j = 0; j < 4; ++j) o[j] = f2bf(v[j]);
  *(u16x4*)(Y + i) = o;
}

__global__ __launch_bounds__(256)
void tril_bf16_kernel(const float* __restrict__ Wt, u16* __restrict__ Y) {
  const int i = blockIdx.x * 256 + threadIdx.x;
  const int s = i >> 9, t = i & 511;
  Y[i] = f2bf(t <= s ? Wt[i] : 0.f);
}

// ---------- BT-layout MFMA GEMM, 256x256 tile, 8-phase counted-vmcnt --------
// C[m,n] = sum_k A[m,k]*B[n,k].  BM=BN=256, BK=64, 512 thr = 8 waves (2Mx4N),
// per-wave 128x64 C (8x4 frags).  LDS: A/B per-K-tile dbuf (parity), 128 KiB.
// Per K-tile, 4 phases (kk = q>>1, n-pair = q&1); each phase:
//   barrier -> sched_barrier -> ds_read (10 or 2 x b128, XOR-swizzled)
//   -> stage-issue -> lgkmcnt(0)+sched_barrier -> setprio(1) 16xMFMA setprio(0)
// Counted waits only: vmcnt(4) once per tile at phase 0 (vmcnt(0) on last tile).
// Stage placement (race-proven via barriers):
//   STAGE_B(t+1) @ phase 0 (dest dbuf's B fully read at end of prev tile ph3);
//   STAGE_A(t+2) @ phase 3 (A(t) last read in ph2; ph3-start barrier proves it).
// FIFO vmcnt (m135): vmcnt(4) leaves A(t+1) in flight, proves A(t),B(t) landed.
// MODE 0: TriU  (z-batched; C=bf16 s = acc+inputs+triu_b[row]; tri K-skip;
//               fused per-block LN2 partial stats)
// MODE 1: fc1   (C=bf16 h = gelu(acc + fc1_b[col]))
// MODE 2: fc2   (C=fp32 out = acc + fc2_b[col] + x2[idx])

template <int MODE>
__global__ __launch_bounds__(512, 2)
void gemm_bt_kernel(const u16* __restrict__ A, const u16* __restrict__ Bm,
                    int K, int lda, int ldb,
                    void* __restrict__ Cp, int ldc,
                    const float* __restrict__ bias,
                    const void* __restrict__ res,
                    long long strideB, long long strideC,
                    float2* __restrict__ stat_part) {
  __shared__ u16 Asb[2 * 16384];   // [dbuf][256 rows][64 k]  (64 KiB)
  __shared__ u16 Bsb[2 * 16384];   // [dbuf][256 rows][64 k]  (64 KiB)
  __shared__ float rs_[8], rq_[8];
  const int tid = threadIdx.x;

  // --- XCD-aware bijective remap (nwg % 8 == 0 for all launches) ---
  const int nwg = gridDim.x;
  const int orig = blockIdx.x;
  const int swz = (orig & 7) * (nwg >> 3) + (orig >> 3);
  int bx, by, bz;
  if (MODE == 0) { bz = swz >> 2; by = (swz >> 1) & 1; bx = swz & 1; }
  else if (MODE == 1) { bz = 0; by = swz >> 2; bx = swz & 3; }
  else { bz = 0; by = swz >> 1; bx = swz & 1; }

  const u16* Bp = Bm + (size_t)bz * (size_t)strideB;
  const int m0 = by * 256, n0 = bx * 256;
  int kTiles = K >> 6;
  if (MODE == 0) { const int need = (by + 1) * 4; if (need < kTiles) kTiles = need; }

  const int lane = tid & 63;
  const int wave = tid >> 6;
  const int wm = (wave >> 2) * 128;   // 2 wave-rows of 128
  const int wn = (wave & 3) * 64;     // 4 wave-cols of 64
  const int lr = lane & 15;
  const int kg = lane >> 4;

  f32x4 acc[8][4];
  const f32x4 zero = {0.f, 0.f, 0.f, 0.f};
#pragma unroll
  for (int m = 0; m < 8; ++m)
#pragma unroll
    for (int n = 0; n < 4; ++n) acc[m][n] = zero;

  // One operand tile = 256 rows x 128B = 2048 16B-chunks = 4 GLD16/thread.
  // Source col-chunk XOR (r&7): LDS dest linear, swizzled ds_reads see linear.
  auto STAGE_A = [&](int t) {
    const int k0 = t << 6;
    const int d = (t & 1) * 16384;
#pragma unroll
    for (int p = 0; p < 4; ++p) {
      const int q = p * 512 + tid;
      const int r = q >> 3;
      const int kcs = (q & 7) ^ (r & 7);
      GLD16(A + (size_t)(m0 + r) * lda + k0 + (kcs << 3), &Asb[d + q * 8]);
    }
  };
  auto STAGE_B = [&](int t) {
    const int k0 = t << 6;
    const int d = (t & 1) * 16384;
#pragma unroll
    for (int p = 0; p < 4; ++p) {
      const int q = p * 512 + tid;
      const int r = q >> 3;
      const int kcs = (q & 7) ^ (r & 7);
      GLD16(Bp + (size_t)(n0 + r) * ldb + k0 + (kcs << 3), &Bsb[d + q * 8]);
    }
  };

  // prologue: 12 loads/thread in flight
  STAGE_A(0); STAGE_B(0); STAGE_A(1);

  s16x8 af[8], bfv[2];
  for (int kt = 0; kt < kTiles; ++kt) {
    const int d = (kt & 1) * 16384;

    // ---- phase 0: kk=0, n={0,1}; counted wait + STAGE_B(kt+1) ----
    if (kt + 1 < kTiles) asm volatile("s_waitcnt vmcnt(4)" ::: "memory");
    else                 asm volatile("s_waitcnt vmcnt(0)" ::: "memory");
    __builtin_amdgcn_s_barrier();
    __builtin_amdgcn_sched_barrier(0);
#pragma unroll
    for (int m = 0; m < 8; ++m) {
      const int row = wm + m * 16 + lr;
      af[m] = *(const s16x8*)&Asb[d + row * 64 + ((kg ^ (row & 7)) << 3)];
    }
#pragma unroll
    for (int n = 0; n < 2; ++n) {
      const int row = wn + n * 16 + lr;
      bfv[n] = *(const s16x8*)&Bsb[d + row * 64 + ((kg ^ (row & 7)) << 3)];
    }
    if (kt + 1 < kTiles) STAGE_B(kt + 1);
    asm volatile("s_waitcnt lgkmcnt(0)" ::: "memory");
    __builtin_amdgcn_sched_barrier(0);
    __builtin_amdgcn_s_setprio(1);
#pragma unroll
    for (int m = 0; m < 8; ++m) {
      acc[m][0] = __builtin_amdgcn_mfma_f32_16x16x32_bf16(af[m], bfv[0], acc[m][0], 0, 0, 0);
      acc[m][1] = __builtin_amdgcn_mfma_f32_16x16x32_bf16(af[m], bfv[1], acc[m][1], 0, 0, 0);
    }
    __builtin_amdgcn_s_setprio(0);

    // ---- phase 1: kk=0, n={2,3} ----
    __builtin_amdgcn_s_barrier();
    __builtin_amdgcn_sched_barrier(0);
#pragma unroll
    for (int n = 0; n < 2; ++n) {
      const int row = wn + (n + 2) * 16 + lr;
      bfv[n] = *(const s16x8*)&Bsb[d + row * 64 + ((kg ^ (row & 7)) << 3)];
    }
    asm volatile("s_waitcnt lgkmcnt(0)" ::: "memory");
    __builtin_amdgcn_sched_barrier(0);
    __builtin_amdgcn_s_setprio(1);
#pragma unroll
    for (int m = 0; m < 8; ++m) {
      acc[m][2] = __builtin_amdgcn_mfma_f32_16x16x32_bf16(af[m], bfv[0], acc[m][2], 0, 0, 0);
      acc[m][3] = __builtin_amdgcn_mfma_f32_16x16x32_bf16(af[m], bfv[1], acc[m][3], 0, 0, 0);
    }
    __builtin_amdgcn_s_setprio(0);

    // ---- phase 2: kk=1, n={0,1} ----
    __builtin_amdgcn_s_barrier();
    __builtin_amdgcn_sched_barrier(0);
#pragma unroll
    for (int m = 0; m < 8; ++m) {
      const int row = wm + m * 16 + lr;
      af[m] = *(const s16x8*)&Asb[d + row * 64 + (((4 + kg) ^ (row & 7)) << 3)];
    }
#pragma unroll
    for (int n = 0; n < 2; ++n) {
      const int row = wn + n * 16 + lr;
      bfv[n] = *(const s16x8*)&Bsb[d + row * 64 + (((4 + kg) ^ (row & 7)) << 3)];
    }
    asm volatile("s_waitcnt lgkmcnt(0)" ::: "memory");
    __builtin_amdgcn_sched_barrier(0);
    __builtin_amdgcn_s_setprio(1);
#pragma unroll
    for (int m = 0; m < 8; ++m) {
      acc[m][0] = __builtin_amdgcn_mfma_f32_16x16x32_bf16(af[m], bfv[0], acc[m][0], 0, 0, 0);
      acc[m][1] = __builtin_amdgcn_mfma_f32_16x16x32_bf16(af[m], bfv[1], acc[m][1], 0, 0, 0);
    }
    __builtin_amdgcn_s_setprio(0);

    // ---- phase 3: kk=1, n={2,3}; STAGE_A(kt+2) (A(kt) consumed in ph2) ----
    __builtin_amdgcn_s_barrier();
    __builtin_amdgcn_sched_barrier(0);
#pragma unroll
    for (int n = 0; n < 2; ++n) {
      const int row = wn + (n + 2) * 16 + lr;
      bfv[n] = *(const s16x8*)&Bsb[d + row * 64 + (((4 + kg) ^ (row & 7)) << 3)];
    }
    if (kt + 2 < kTiles) STAGE_A(kt + 2);
    asm volatile("s_waitcnt lgkmcnt(0)" ::: "memory");
    __builtin_amdgcn_sched_barrier(0);
    __builtin_amdgcn_s_setprio(1);
#pragma unroll
    for (int m = 0; m < 8; ++m) {
      acc[m][2] = __builtin_amdgcn_mfma_f32_16x16x32_bf16(af[m], bfv[0], acc[m][2], 0, 0, 0);
      acc[m][3] = __builtin_amdgcn_mfma_f32_16x16x32_bf16(af[m], bfv[1], acc[m][3], 0, 0, 0);
    }
    __builtin_amdgcn_s_setprio(0);
  }

  if (MODE == 0) {
    u16* Cptr = (u16*)Cp + (size_t)bz * (size_t)strideC;
    const float* inp = (const float*)res + (size_t)bz * (size_t)strideC;
    float psum = 0.f, psq = 0.f;
#pragma unroll
    for (int m = 0; m < 8; ++m) {
      const int rb = m0 + wm + m * 16 + kg * 4;
#pragma unroll
      for (int n = 0; n < 4; ++n) {
        const int col = n0 + wn + n * 16 + lr;
#pragma unroll
        for (int j = 0; j < 4; ++j) {
          const size_t idx = (size_t)(rb + j) * ldc + col;
          float v = acc[m][n][j] + inp[idx] + bias[rb + j];
          psum += v; psq += v * v;
          Cptr[idx] = f2bf(v);
        }
      }
    }
    for (int o = 32; o; o >>= 1) { psum += __shfl_down(psum, o); psq += __shfl_down(psq, o); }
    if (lane == 0) { rs_[wave] = psum; rq_[wave] = psq; }
    __syncthreads();
    if (tid == 0) {
      float s = 0.f, q = 0.f;
#pragma unroll
      for (int w = 0; w < 8; ++w) { s += rs_[w]; q += rq_[w]; }
      stat_part[(size_t)bz * 4 + by * 2 + bx] = make_float2(s, q);
    }
  } else if (MODE == 1) {
    u16* Cptr = (u16*)Cp;
#pragma unroll
    for (int m = 0; m < 8; ++m) {
      const int rb = m0 + wm + m * 16 + kg * 4;
#pragma unroll
      for (int n = 0; n < 4; ++n) {
        const int col = n0 + wn + n * 16 + lr;
        const float bs = bias[col];
#pragma unroll
        for (int j = 0; j < 4; ++j) {
          float v = acc[m][n][j] + bs;
          Cptr[(size_t)(rb + j) * ldc + col] = f2bf(gelu_fast(v));
        }
      }
    }
  } else {
    float* Cptr = (float*)Cp;
    const u16* x2p = (const u16*)res;
#pragma unroll
    for (int m = 0; m < 8; ++m) {
      const int rb = m0 + wm + m * 16 + kg * 4;
#pragma unroll
      for (int n = 0; n < 4; ++n) {
        const int col = n0 + wn + n * 16 + lr;
        const float bs = bias[col];
#pragma unroll
        for (int j = 0; j < 4; ++j) {
          const size_t idx = (size_t)(rb + j) * ldc + col;
          Cptr[idx] = acc[m][n][j] + bs + bf2f(x2p[idx]);
        }
      }
    }
  }
}

// -------------------------------- launcher ---------------------------------

extern "C" void kernel_launch(void* const* d_in, const int* in_sizes, int n_in,
                              void* d_out, int out_size, void* d_ws, size_t ws_size,
                              hipStream_t stream) {
  const float* inputs = (const float*)d_in[0];
  const float* ln1_w  = (const float*)d_in[1];
  const float* ln1_b  = (const float*)d_in[2];
  const float* ln2_w  = (const float*)d_in[3];
  const float* ln2_b  = (const float*)d_in[4];
  const float* triu_W = (const float*)d_in[5];
  const float* triu_b = (const float*)d_in[6];
  const float* fc1_W  = (const float*)d_in[7];
  const float* fc1_b  = (const float*)d_in[8];
  const float* fc2_W  = (const float*)d_in[9];
  const float* fc2_b  = (const float*)d_in[10];
  float* out = (float*)d_out;
  (void)in_sizes; (void)n_in; (void)out_size; (void)ws_size;

  char* ws = (char*)d_ws;
  size_t off = 0;
  auto carve = [&](size_t bytes) {
    char* p = ws + off;
    off += (bytes + 255) & ~(size_t)255;
    return p;
  };
  u16* s_bf = (u16*)carve((size_t)B_ * T_ * C_ * 2);   // 67MB bf16 s = mix+inputs+bias
  u16* xT   = (u16*)carve((size_t)B_ * T_ * C_ * 2);   // 67MB; reused as x2
  u16* x2   = xT;
  u16* h    = (u16*)carve((size_t)B_ * T_ * 2 * C_ * 2); // 134MB bf16
  u16* wmb  = (u16*)carve((size_t)T_ * T_ * 2);
  u16* w1b  = (u16*)carve((size_t)2 * C_ * C_ * 2);
  u16* w2b  = (u16*)carve((size_t)C_ * 2 * C_ * 2);
  float2* partials  = (float2*)carve(128 * 128 * sizeof(float2));
  float2* partials2 = (float2*)carve(128 * 4 * sizeof(float2));
  float2* stats1 = (float2*)carve(128 * sizeof(float2));
  float2* stats2 = (float2*)carve(128 * sizeof(float2));

  // LN1 stats
  reduce_stats_kernel<<<dim3(128, 128), 256, 0, stream>>>(inputs, partials);
  finalize_stats_kernel<<<128, 128, 0, stream>>>(partials, stats1);
  // LN1 apply + transpose -> xT (bf16)
  ln1_transpose_kernel<<<dim3(8, 8, 128), 256, 0, stream>>>(inputs, ln1_w, ln1_b, stats1, xT);
  // weight prep
  tril_bf16_kernel<<<1024, 256, 0, stream>>>(triu_W, wmb);
  cvt_bf16_kernel<<<512, 256, 0, stream>>>(fc1_W, w1b);
  cvt_bf16_kernel<<<512, 256, 0, stream>>>(fc2_W, w2b);
  // TriU mix: s = tril(W) @ x + triu_b + inputs (bf16 out) + fused LN2 partial stats
  gemm_bt_kernel<0><<<512, 512, 0, stream>>>(
      wmb, xT, 512, 512, 512, s_bf, 512, triu_b, inputs, (long long)TC, (long long)TC, partials2);
  finalize_stats4_kernel<<<128, 64, 0, stream>>>(partials2, stats2);
  // LN2 apply -> x2 (bf16)
  ln2_apply_kernel<<<16384, 256, 0, stream>>>(s_bf, ln2_w, ln2_b, stats2, x2);
  // fc1 + GELU -> h (bf16)
  gemm_bt_kernel<1><<<1024, 512, 0, stream>>>(
      x2, w1b, 512, 512, 512, h, 1024, fc1_b, nullptr, 0, 0, nullptr);
  // fc2 + bias + residual -> out (fp32)
  gemm_bt_kernel<2><<<512, 512, 0, stream>>>(
      h, w2b, 1024, 1024, 1024, out, 512, fc2_b, x2, 0, 0, nullptr);
}